// Round 1
// baseline (110.716 us; speedup 1.0000x reference)
//
#include <hip/hip_runtime.h>

// SpatioTemporalGAT  (N=4096, F=64, H=64, K=2 heads, O=32; temporal input unused)
//
// A: gat_prep  — Wh[k] = X @ W_gat[k]^T (fp32); store transposed bf16 WhT[k][h][n];
//                s_src[k][n] = Wh.a_src, s_dst[k][n] = Wh.a_dst.
// B: gat_attn  — fused masked softmax + PV via mfma_f32_16x16x32_bf16.
//                No max-subtraction needed (logits bounded ~±2):
//                w = adj ? exp(lrelu(sd+ss)) : 0 ; h' = elu( (Σ_q w·Wh[q]) / Σ_q w ).
//                Block = 16-row tile, 16 waves × 256-q slices; w generated
//                in-register in A-frag layout (row=l&15, k=(l>>4)*8+j);
//                B-frag read directly from WhT (contiguous along q).
//                Cross-wave combine in LDS; writes h[n][k*64+h] fp32.
// C: lstm_fc   — 1-step LSTM (h0=c0=0 => forget gate dead) + fc.

#define NN 4096

typedef __attribute__((ext_vector_type(8))) short bf16x8;
typedef __attribute__((ext_vector_type(4))) float f32x4;

__device__ inline unsigned short bf_rne(float f) {
    unsigned u = __float_as_uint(f);
    u += 0x7fffu + ((u >> 16) & 1u);
    return (unsigned short)(u >> 16);
}

__global__ __launch_bounds__(256) void gat_prep(
    const float* __restrict__ X, const float* __restrict__ Wg,
    const float* __restrict__ a_src, const float* __restrict__ a_dst,
    unsigned short* __restrict__ whT, float* __restrict__ ssrc,
    float* __restrict__ sdst)
{
    __shared__ float X_lds[64][64];
    __shared__ float Wh_lds[64][65];   // +1 pad: conflict-free column reads
    __shared__ float spart[64][4][2];
    const int t = threadIdx.x;
    const int n0 = blockIdx.x * 64;
#pragma unroll
    for (int i = 0; i < 16; ++i) {
        int idx = t + i * 256;
        X_lds[idx >> 6][idx & 63] = X[n0 * 64 + idx];
    }
    __syncthreads();
    const int h = t & 63, rg = t >> 6;
    for (int k = 0; k < 2; ++k) {
        float acc[16];
#pragma unroll
        for (int r = 0; r < 16; ++r) acc[r] = 0.f;
        for (int f0 = 0; f0 < 64; f0 += 4) {
            const float4 w4 = *(const float4*)&Wg[(k * 64 + h) * 64 + f0];
#pragma unroll
            for (int r = 0; r < 16; ++r) {
                const float4 x4 = *(const float4*)&X_lds[rg * 16 + r][f0];
                acc[r] += w4.x * x4.x + w4.y * x4.y + w4.z * x4.z + w4.w * x4.w;
            }
        }
        if (k) __syncthreads();   // protect previous head's spart readers
#pragma unroll
        for (int r = 0; r < 16; ++r) Wh_lds[rg * 16 + r][h] = acc[r];
        __syncthreads();
        {   // per-node logit terms (partial over 16 h each)
            const int r = t & 63, qa = t >> 6;
            float ps = 0.f, pd = 0.f;
#pragma unroll
            for (int i = 0; i < 16; ++i) {
                const int hh = qa * 16 + i;
                const float v = Wh_lds[r][hh];
                ps += v * a_src[k * 64 + hh];
                pd += v * a_dst[k * 64 + hh];
            }
            spart[r][qa][0] = ps;
            spart[r][qa][1] = pd;
        }
        {   // transposed bf16 store: whT[k][h][n]
            const int hw = t >> 2, c = t & 3;
            unsigned pk[8];
#pragma unroll
            for (int i = 0; i < 8; ++i) {
                unsigned lo = bf_rne(Wh_lds[c * 16 + 2 * i][hw]);
                unsigned hi = bf_rne(Wh_lds[c * 16 + 2 * i + 1][hw]);
                pk[i] = lo | (hi << 16);
            }
            uint4* dst = (uint4*)&whT[(k * 64 + hw) * NN + n0 + c * 16];
            dst[0] = make_uint4(pk[0], pk[1], pk[2], pk[3]);
            dst[1] = make_uint4(pk[4], pk[5], pk[6], pk[7]);
        }
        __syncthreads();
        if (t < 64) {
            float s0 = spart[t][0][0] + spart[t][1][0] + spart[t][2][0] + spart[t][3][0];
            float s1 = spart[t][0][1] + spart[t][1][1] + spart[t][2][1] + spart[t][3][1];
            ssrc[k * NN + n0 + t] = s0;
            sdst[k * NN + n0 + t] = s1;
        }
    }
}

__global__ __launch_bounds__(1024) void gat_attn(
    const int* __restrict__ adj, const unsigned short* __restrict__ whT,
    const float* __restrict__ ssrc, const float* __restrict__ sdst,
    float* __restrict__ h_out)
{
    __shared__ float S_all[16][2][16][64];   // 128 KB: per-wave partial PV
    __shared__ float z_all[16][2][16];       // per-wave partial denominators
    const int tid = threadIdx.x;
    const int wave = tid >> 6, lane = tid & 63;
    const int rloc = lane & 15, qg = lane >> 4;
    const int p = blockIdx.x * 16 + rloc;          // A-frag row for this lane
    const int* __restrict__ adj_row = adj + (long)p * NN;
    const float sd0 = sdst[p], sd1 = sdst[NN + p];

    const unsigned short* bptr[2][4];
#pragma unroll
    for (int k = 0; k < 2; ++k)
#pragma unroll
        for (int f = 0; f < 4; ++f)
            bptr[k][f] = whT + (k * 64 + f * 16 + rloc) * NN;

    f32x4 acc[2][4];
#pragma unroll
    for (int k = 0; k < 2; ++k)
#pragma unroll
        for (int f = 0; f < 4; ++f)
            acc[k][f] = (f32x4){0.f, 0.f, 0.f, 0.f};
    float z0 = 0.f, z1 = 0.f;

    const int qbase = wave * 256;   // each wave owns a 256-wide q slice
    for (int chunk = 0; chunk < 4; ++chunk) {
#pragma unroll
        for (int kk = 0; kk < 2; ++kk) {       // two K=32 steps per 64-q chunk
            const int q0 = qbase + chunk * 64 + kk * 32 + qg * 8;
            const int4 a0 = *(const int4*)(adj_row + q0);
            const int4 a1 = *(const int4*)(adj_row + q0 + 4);
            const float4 sa0 = *(const float4*)(ssrc + q0);
            const float4 sa1 = *(const float4*)(ssrc + q0 + 4);
            const float4 sb0 = *(const float4*)(ssrc + NN + q0);
            const float4 sb1 = *(const float4*)(ssrc + NN + q0 + 4);
            const int am[8] = {a0.x, a0.y, a0.z, a0.w, a1.x, a1.y, a1.z, a1.w};
            const float s0v[8] = {sa0.x, sa0.y, sa0.z, sa0.w, sa1.x, sa1.y, sa1.z, sa1.w};
            const float s1v[8] = {sb0.x, sb0.y, sb0.z, sb0.w, sb1.x, sb1.y, sb1.z, sb1.w};
            union { bf16x8 v; unsigned short u[8]; } fa0, fa1;
#pragma unroll
            for (int j = 0; j < 8; ++j) {
                float e0 = sd0 + s0v[j];
                e0 = fmaxf(e0, 0.2f * e0);                      // leaky_relu(.,0.2)
                const float w0 = (am[j] > 0) ? __expf(e0) : 0.f;
                z0 += w0;
                fa0.u[j] = bf_rne(w0);
                float e1 = sd1 + s1v[j];
                e1 = fmaxf(e1, 0.2f * e1);
                const float w1 = (am[j] > 0) ? __expf(e1) : 0.f;
                z1 += w1;
                fa1.u[j] = bf_rne(w1);
            }
#pragma unroll
            for (int f = 0; f < 4; ++f) {
                const bf16x8 b0 = *(const bf16x8*)(bptr[0][f] + q0);
                acc[0][f] = __builtin_amdgcn_mfma_f32_16x16x32_bf16(fa0.v, b0, acc[0][f], 0, 0, 0);
                const bf16x8 b1 = *(const bf16x8*)(bptr[1][f] + q0);
                acc[1][f] = __builtin_amdgcn_mfma_f32_16x16x32_bf16(fa1.v, b1, acc[1][f], 0, 0, 0);
            }
        }
    }
    // z: sum the 4 q-groups (lanes l, l^16, l^32, l^48 share a row)
    z0 += __shfl_xor(z0, 16); z0 += __shfl_xor(z0, 32);
    z1 += __shfl_xor(z1, 16); z1 += __shfl_xor(z1, 32);
    if (lane < 16) { z_all[wave][0][lane] = z0; z_all[wave][1][lane] = z1; }
    // D-frag layout: row=(l>>4)*4+j, col=l&15
#pragma unroll
    for (int k = 0; k < 2; ++k)
#pragma unroll
        for (int f = 0; f < 4; ++f)
#pragma unroll
            for (int j = 0; j < 4; ++j)
                S_all[wave][k][qg * 4 + j][f * 16 + rloc] = acc[k][f][j];
    __syncthreads();
    // combine 16 wave-partials, normalize, elu, write h[n][k*64+h]
#pragma unroll
    for (int i = 0; i < 2; ++i) {
        const int idx = tid + i * 1024;
        const int k = idx >> 10, rr = (idx >> 6) & 15, hh = idx & 63;
        float s = 0.f, z = 0.f;
#pragma unroll
        for (int w = 0; w < 16; ++w) {
            s += S_all[w][k][rr][hh];
            z += z_all[w][k][rr];
        }
        float v = s / z;
        v = v > 0.f ? v : expm1f(v);
        h_out[(blockIdx.x * 16 + rr) * 128 + k * 64 + hh] = v;
    }
}

__global__ __launch_bounds__(256) void lstm_fc(
    const float* __restrict__ h_in, const float* __restrict__ W_ih,
    const float* __restrict__ b_ih, const float* __restrict__ b_hh,
    const float* __restrict__ fc_W, const float* __restrict__ fc_b,
    float* __restrict__ out)
{
    __shared__ float hbuf[4][128];
    __shared__ float htb[4][64];
    const int tid = threadIdx.x, wave = tid >> 6, lane = tid & 63;
    const int n = blockIdx.x * 4 + wave;
    hbuf[wave][lane] = h_in[n * 128 + lane];
    hbuf[wave][lane + 64] = h_in[n * 128 + 64 + lane];
    __syncthreads();
    // gates i,f,g,o ; f*c0 == 0 so f is skipped
    float si = b_ih[lane] + b_hh[lane];
    float sg = b_ih[128 + lane] + b_hh[128 + lane];
    float so = b_ih[192 + lane] + b_hh[192 + lane];
    const float* __restrict__ wi = W_ih + lane * 128;
    const float* __restrict__ wg = W_ih + (128 + lane) * 128;
    const float* __restrict__ wo = W_ih + (192 + lane) * 128;
    for (int m = 0; m < 128; m += 4) {
        const float4 hv = *(const float4*)&hbuf[wave][m];
        const float4 A = *(const float4*)(wi + m);
        const float4 B = *(const float4*)(wg + m);
        const float4 C = *(const float4*)(wo + m);
        si += A.x * hv.x + A.y * hv.y + A.z * hv.z + A.w * hv.w;
        sg += B.x * hv.x + B.y * hv.y + B.z * hv.z + B.w * hv.w;
        so += C.x * hv.x + C.y * hv.y + C.z * hv.z + C.w * hv.w;
    }
    const float cc = (1.f / (1.f + __expf(-si))) * tanhf(sg);
    const float ht = (1.f / (1.f + __expf(-so))) * tanhf(cc);
    htb[wave][lane] = ht;
    __syncthreads();
    if (lane < 32) {
        float acc = fc_b[lane];
        const float* __restrict__ fw = fc_W + lane * 64;
#pragma unroll 8
        for (int hh = 0; hh < 64; ++hh) acc += fw[hh] * htb[wave][hh];
        out[n * 32 + lane] = acc;
    }
}

extern "C" void kernel_launch(void* const* d_in, const int* in_sizes, int n_in,
                              void* d_out, int out_size, void* d_ws, size_t ws_size,
                              hipStream_t stream) {
    const float* X     = (const float*)d_in[0];
    const int*   adj   = (const int*)d_in[1];
    // d_in[2] temporal_features: unused by the reference
    const float* Wg    = (const float*)d_in[3];
    const float* a_src = (const float*)d_in[4];
    const float* a_dst = (const float*)d_in[5];
    const float* W_ih  = (const float*)d_in[6];
    // d_in[7] W_hh: unused (h0 == 0)
    const float* b_ih  = (const float*)d_in[8];
    const float* b_hh  = (const float*)d_in[9];
    const float* fc_W  = (const float*)d_in[10];
    const float* fc_b  = (const float*)d_in[11];
    float* out = (float*)d_out;

    char* ws = (char*)d_ws;
    unsigned short* whT = (unsigned short*)ws;           // K*H*N bf16 = 1 MB
    float* ssrc = (float*)(ws + (1 << 20));              // K*N f32 = 32 KB
    float* sdst = (float*)(ws + (1 << 20) + (32 << 10)); // 32 KB
    float* hbuf = (float*)(ws + (1 << 20) + (64 << 10)); // N*128 f32 = 2 MB

    hipLaunchKernelGGL(gat_prep, dim3(64), dim3(256), 0, stream,
                       X, Wg, a_src, a_dst, whT, ssrc, sdst);
    hipLaunchKernelGGL(gat_attn, dim3(256), dim3(1024), 0, stream,
                       adj, whT, ssrc, sdst, hbuf);
    hipLaunchKernelGGL(lstm_fc, dim3(1024), dim3(256), 0, stream,
                       hbuf, W_ih, b_ih, b_hh, fc_W, fc_b, out);
}

// Round 2
// 77.290 us; speedup vs baseline: 1.4325x; 1.4325x over previous
//
#include <hip/hip_runtime.h>

// SpatioTemporalGAT  (N=4096, F=64, H=64, K=2 heads, O=32; temporal input unused)
//
// convert_w — pack LSTM weights: Wpk[192][128] bf16 (gate rows i,g,o; f is dead
//             since c0=0), fcb[32][64] bf16, biasg[192] = b_ih+b_hh (i,g,o).
// gat_prep  — Wh[k] = X @ W_gat[k]^T (fp32); store transposed bf16 WhT[k][h][n];
//             s_src[k][n] = Wh.a_src, s_dst[k][n] = Wh.a_dst.
// gat_attn  — fused masked softmax + PV via mfma_f32_16x16x32_bf16.
//             No max-subtraction needed (logits bounded ~±2):
//             w = adj ? exp(lrelu(sd+ss)) : 0 ; h' = elu( (Σ_q w·Wh[q]) / Σ_q w ).
//             Writes h as bf16 [n][k*64+h] (only consumer is the gates GEMM).
// lstm_fc2  — gates GEMM [16x192x128] per block via MFMA (fixes R1's 54µs
//             uncoalesced GEMV: lane-per-row W reads were 64-way scattered),
//             fused sigmoid/tanh epilogue in D-frag layout, fc via 4 MFMA,
//             coalesced store through LDS.

#define NN 4096

typedef __attribute__((ext_vector_type(8))) short bf16x8;
typedef __attribute__((ext_vector_type(4))) float f32x4;

__device__ inline unsigned short bf_rne(float f) {
    unsigned u = __float_as_uint(f);
    u += 0x7fffu + ((u >> 16) & 1u);
    return (unsigned short)(u >> 16);
}

__device__ inline float sigf(float x) { return 1.f / (1.f + __expf(-x)); }

__global__ __launch_bounds__(256) void convert_w(
    const float* __restrict__ W_ih, const float* __restrict__ b_ih,
    const float* __restrict__ b_hh, const float* __restrict__ fc_W,
    unsigned short* __restrict__ Wpk, unsigned short* __restrict__ fcb,
    float* __restrict__ biasg)
{
    const int idx = blockIdx.x * 256 + threadIdx.x;
    if (idx < 24576) {
        const int jj = idx >> 7, m = idx & 127;
        const int sr = (jj < 64) ? jj : 64 + jj;   // i rows 0-63, g 128-191, o 192-255
        Wpk[idx] = bf_rne(W_ih[sr * 128 + m]);
    } else if (idx < 26624) {
        const int i2 = idx - 24576;
        fcb[i2] = bf_rne(fc_W[i2]);
    } else if (idx < 26816) {
        const int j = idx - 26624;
        const int sr = (j < 64) ? j : 64 + j;
        biasg[j] = b_ih[sr] + b_hh[sr];
    }
}

__global__ __launch_bounds__(256) void gat_prep(
    const float* __restrict__ X, const float* __restrict__ Wg,
    const float* __restrict__ a_src, const float* __restrict__ a_dst,
    unsigned short* __restrict__ whT, float* __restrict__ ssrc,
    float* __restrict__ sdst)
{
    __shared__ float X_lds[64][64];
    __shared__ float Wh_lds[64][65];   // +1 pad: conflict-free column reads
    __shared__ float spart[64][4][2];
    const int t = threadIdx.x;
    const int n0 = blockIdx.x * 64;
#pragma unroll
    for (int i = 0; i < 16; ++i) {
        int idx = t + i * 256;
        X_lds[idx >> 6][idx & 63] = X[n0 * 64 + idx];
    }
    __syncthreads();
    const int h = t & 63, rg = t >> 6;
    for (int k = 0; k < 2; ++k) {
        float acc[16];
#pragma unroll
        for (int r = 0; r < 16; ++r) acc[r] = 0.f;
        for (int f0 = 0; f0 < 64; f0 += 4) {
            const float4 w4 = *(const float4*)&Wg[(k * 64 + h) * 64 + f0];
#pragma unroll
            for (int r = 0; r < 16; ++r) {
                const float4 x4 = *(const float4*)&X_lds[rg * 16 + r][f0];
                acc[r] += w4.x * x4.x + w4.y * x4.y + w4.z * x4.z + w4.w * x4.w;
            }
        }
        if (k) __syncthreads();   // protect previous head's spart readers
#pragma unroll
        for (int r = 0; r < 16; ++r) Wh_lds[rg * 16 + r][h] = acc[r];
        __syncthreads();
        {   // per-node logit terms (partial over 16 h each)
            const int r = t & 63, qa = t >> 6;
            float ps = 0.f, pd = 0.f;
#pragma unroll
            for (int i = 0; i < 16; ++i) {
                const int hh = qa * 16 + i;
                const float v = Wh_lds[r][hh];
                ps += v * a_src[k * 64 + hh];
                pd += v * a_dst[k * 64 + hh];
            }
            spart[r][qa][0] = ps;
            spart[r][qa][1] = pd;
        }
        {   // transposed bf16 store: whT[k][h][n]
            const int hw = t >> 2, c = t & 3;
            unsigned pk[8];
#pragma unroll
            for (int i = 0; i < 8; ++i) {
                unsigned lo = bf_rne(Wh_lds[c * 16 + 2 * i][hw]);
                unsigned hi = bf_rne(Wh_lds[c * 16 + 2 * i + 1][hw]);
                pk[i] = lo | (hi << 16);
            }
            uint4* dst = (uint4*)&whT[(k * 64 + hw) * NN + n0 + c * 16];
            dst[0] = make_uint4(pk[0], pk[1], pk[2], pk[3]);
            dst[1] = make_uint4(pk[4], pk[5], pk[6], pk[7]);
        }
        __syncthreads();
        if (t < 64) {
            float s0 = spart[t][0][0] + spart[t][1][0] + spart[t][2][0] + spart[t][3][0];
            float s1 = spart[t][0][1] + spart[t][1][1] + spart[t][2][1] + spart[t][3][1];
            ssrc[k * NN + n0 + t] = s0;
            sdst[k * NN + n0 + t] = s1;
        }
    }
}

__global__ __launch_bounds__(1024) void gat_attn(
    const int* __restrict__ adj, const unsigned short* __restrict__ whT,
    const float* __restrict__ ssrc, const float* __restrict__ sdst,
    unsigned short* __restrict__ h_bf)
{
    __shared__ float S_all[16][2][16][64];   // 128 KB: per-wave partial PV
    __shared__ float z_all[16][2][16];       // per-wave partial denominators
    const int tid = threadIdx.x;
    const int wave = tid >> 6, lane = tid & 63;
    const int rloc = lane & 15, qg = lane >> 4;
    const int p = blockIdx.x * 16 + rloc;          // A-frag row for this lane
    const int* __restrict__ adj_row = adj + (long)p * NN;
    const float sd0 = sdst[p], sd1 = sdst[NN + p];

    const unsigned short* bptr[2][4];
#pragma unroll
    for (int k = 0; k < 2; ++k)
#pragma unroll
        for (int f = 0; f < 4; ++f)
            bptr[k][f] = whT + (k * 64 + f * 16 + rloc) * NN;

    f32x4 acc[2][4];
#pragma unroll
    for (int k = 0; k < 2; ++k)
#pragma unroll
        for (int f = 0; f < 4; ++f)
            acc[k][f] = (f32x4){0.f, 0.f, 0.f, 0.f};
    float z0 = 0.f, z1 = 0.f;

    const int qbase = wave * 256;   // each wave owns a 256-wide q slice
    for (int chunk = 0; chunk < 4; ++chunk) {
#pragma unroll
        for (int kk = 0; kk < 2; ++kk) {       // two K=32 steps per 64-q chunk
            const int q0 = qbase + chunk * 64 + kk * 32 + qg * 8;
            const int4 a0 = *(const int4*)(adj_row + q0);
            const int4 a1 = *(const int4*)(adj_row + q0 + 4);
            const float4 sa0 = *(const float4*)(ssrc + q0);
            const float4 sa1 = *(const float4*)(ssrc + q0 + 4);
            const float4 sb0 = *(const float4*)(ssrc + NN + q0);
            const float4 sb1 = *(const float4*)(ssrc + NN + q0 + 4);
            const int am[8] = {a0.x, a0.y, a0.z, a0.w, a1.x, a1.y, a1.z, a1.w};
            const float s0v[8] = {sa0.x, sa0.y, sa0.z, sa0.w, sa1.x, sa1.y, sa1.z, sa1.w};
            const float s1v[8] = {sb0.x, sb0.y, sb0.z, sb0.w, sb1.x, sb1.y, sb1.z, sb1.w};
            union { bf16x8 v; unsigned short u[8]; } fa0, fa1;
#pragma unroll
            for (int j = 0; j < 8; ++j) {
                float e0 = sd0 + s0v[j];
                e0 = fmaxf(e0, 0.2f * e0);                      // leaky_relu(.,0.2)
                const float w0 = (am[j] > 0) ? __expf(e0) : 0.f;
                z0 += w0;
                fa0.u[j] = bf_rne(w0);
                float e1 = sd1 + s1v[j];
                e1 = fmaxf(e1, 0.2f * e1);
                const float w1 = (am[j] > 0) ? __expf(e1) : 0.f;
                z1 += w1;
                fa1.u[j] = bf_rne(w1);
            }
#pragma unroll
            for (int f = 0; f < 4; ++f) {
                const bf16x8 b0 = *(const bf16x8*)(bptr[0][f] + q0);
                acc[0][f] = __builtin_amdgcn_mfma_f32_16x16x32_bf16(fa0.v, b0, acc[0][f], 0, 0, 0);
                const bf16x8 b1 = *(const bf16x8*)(bptr[1][f] + q0);
                acc[1][f] = __builtin_amdgcn_mfma_f32_16x16x32_bf16(fa1.v, b1, acc[1][f], 0, 0, 0);
            }
        }
    }
    // z: sum the 4 q-groups (lanes l, l^16, l^32, l^48 share a row)
    z0 += __shfl_xor(z0, 16); z0 += __shfl_xor(z0, 32);
    z1 += __shfl_xor(z1, 16); z1 += __shfl_xor(z1, 32);
    if (lane < 16) { z_all[wave][0][lane] = z0; z_all[wave][1][lane] = z1; }
    // D-frag layout: row=(l>>4)*4+j, col=l&15
#pragma unroll
    for (int k = 0; k < 2; ++k)
#pragma unroll
        for (int f = 0; f < 4; ++f)
#pragma unroll
            for (int j = 0; j < 4; ++j)
                S_all[wave][k][qg * 4 + j][f * 16 + rloc] = acc[k][f][j];
    __syncthreads();
    // combine 16 wave-partials, normalize, elu, write h_bf[n][k*64+h] (bf16)
#pragma unroll
    for (int i = 0; i < 2; ++i) {
        const int idx = tid + i * 1024;
        const int k = idx >> 10, rr = (idx >> 6) & 15, hh = idx & 63;
        float s = 0.f, z = 0.f;
#pragma unroll
        for (int w = 0; w < 16; ++w) {
            s += S_all[w][k][rr][hh];
            z += z_all[w][k][rr];
        }
        float v = s / z;
        v = v > 0.f ? v : expm1f(v);
        h_bf[(blockIdx.x * 16 + rr) * 128 + k * 64 + hh] = bf_rne(v);
    }
}

// One wave per block, 16 nodes. gates[16,192] = h[16,128] @ Wpk^T via 48 MFMA;
// i/g/o of the same (node,h) live in the same lane (tiles t, 4+t, 8+t), so the
// LSTM nonlinearity is pure per-lane VALU. Then fc via 4 MFMA.
__global__ __launch_bounds__(64) void lstm_fc2(
    const unsigned short* __restrict__ h_bf, const unsigned short* __restrict__ Wpk,
    const unsigned short* __restrict__ fcb, const float* __restrict__ biasg,
    const float* __restrict__ fc_b, float* __restrict__ out)
{
    __shared__ unsigned short ht_lds[16][72];   // pad 72: 2-way-max bank aliasing
    __shared__ float out_lds[16][32];
    const int l = threadIdx.x;
    const int c = l & 15, g4 = l >> 4;
    const int n0 = blockIdx.x * 16;

    f32x4 acc[12];
#pragma unroll
    for (int t = 0; t < 12; ++t) acc[t] = (f32x4){0.f, 0.f, 0.f, 0.f};
#pragma unroll
    for (int k0 = 0; k0 < 4; ++k0) {
        const bf16x8 afrag = *(const bf16x8*)&h_bf[(n0 + c) * 128 + k0 * 32 + g4 * 8];
#pragma unroll
        for (int t = 0; t < 12; ++t) {
            const bf16x8 b = *(const bf16x8*)&Wpk[(t * 16 + c) * 128 + k0 * 32 + g4 * 8];
            acc[t] = __builtin_amdgcn_mfma_f32_16x16x32_bf16(afrag, b, acc[t], 0, 0, 0);
        }
    }
    // D-frag: row(node) = g4*4+j, col = c. gate value for (node, h=t*16+c).
#pragma unroll
    for (int t = 0; t < 4; ++t) {
        const float bi = biasg[t * 16 + c];
        const float bg = biasg[64 + t * 16 + c];
        const float bo = biasg[128 + t * 16 + c];
#pragma unroll
        for (int j = 0; j < 4; ++j) {
            const float iv = acc[t][j] + bi;
            const float gv = acc[4 + t][j] + bg;
            const float ov = acc[8 + t][j] + bo;
            const float cc = sigf(iv) * tanhf(gv);
            const float ht = sigf(ov) * tanhf(cc);
            ht_lds[g4 * 4 + j][t * 16 + c] = bf_rne(ht);
        }
    }
    __syncthreads();
    f32x4 acc2[2];
#pragma unroll
    for (int t = 0; t < 2; ++t) acc2[t] = (f32x4){0.f, 0.f, 0.f, 0.f};
#pragma unroll
    for (int k0 = 0; k0 < 2; ++k0) {
        const bf16x8 a2 = *(const bf16x8*)&ht_lds[c][k0 * 32 + g4 * 8];
#pragma unroll
        for (int t = 0; t < 2; ++t) {
            const bf16x8 b2 = *(const bf16x8*)&fcb[(t * 16 + c) * 64 + k0 * 32 + g4 * 8];
            acc2[t] = __builtin_amdgcn_mfma_f32_16x16x32_bf16(a2, b2, acc2[t], 0, 0, 0);
        }
    }
#pragma unroll
    for (int t = 0; t < 2; ++t) {
        const float fb = fc_b[t * 16 + c];
#pragma unroll
        for (int j = 0; j < 4; ++j)
            out_lds[g4 * 4 + j][t * 16 + c] = acc2[t][j] + fb;
    }
    __syncthreads();
#pragma unroll
    for (int i = 0; i < 8; ++i) {
        const int idx = l + i * 64;
        out[n0 * 32 + idx] = out_lds[idx >> 5][idx & 31];
    }
}

extern "C" void kernel_launch(void* const* d_in, const int* in_sizes, int n_in,
                              void* d_out, int out_size, void* d_ws, size_t ws_size,
                              hipStream_t stream) {
    const float* X     = (const float*)d_in[0];
    const int*   adj   = (const int*)d_in[1];
    // d_in[2] temporal_features: unused by the reference
    const float* Wg    = (const float*)d_in[3];
    const float* a_src = (const float*)d_in[4];
    const float* a_dst = (const float*)d_in[5];
    const float* W_ih  = (const float*)d_in[6];
    // d_in[7] W_hh: unused (h0 == 0)
    const float* b_ih  = (const float*)d_in[8];
    const float* b_hh  = (const float*)d_in[9];
    const float* fc_W  = (const float*)d_in[10];
    const float* fc_b  = (const float*)d_in[11];
    float* out = (float*)d_out;

    char* ws = (char*)d_ws;
    unsigned short* whT = (unsigned short*)ws;                     // 1 MB
    float* ssrc = (float*)(ws + (1 << 20));                        // 32 KB
    float* sdst = (float*)(ws + (1 << 20) + (32 << 10));           // 32 KB
    unsigned short* h_bf = (unsigned short*)(ws + (1 << 20) + (64 << 10)); // 1 MB
    char* ws2 = ws + (2 << 20) + (64 << 10);
    unsigned short* Wpk = (unsigned short*)ws2;                    // 48 KB
    unsigned short* fcb = (unsigned short*)(ws2 + (48 << 10));     // 4 KB
    float* biasg = (float*)(ws2 + (52 << 10));                     // 768 B

    hipLaunchKernelGGL(convert_w, dim3(105), dim3(256), 0, stream,
                       W_ih, b_ih, b_hh, fc_W, Wpk, fcb, biasg);
    hipLaunchKernelGGL(gat_prep, dim3(64), dim3(256), 0, stream,
                       X, Wg, a_src, a_dst, whT, ssrc, sdst);
    hipLaunchKernelGGL(gat_attn, dim3(256), dim3(1024), 0, stream,
                       adj, whT, ssrc, sdst, h_bf);
    hipLaunchKernelGGL(lstm_fc2, dim3(256), dim3(64), 0, stream,
                       h_bf, Wpk, fcb, biasg, fc_b, out);
}

// Round 3
// 69.213 us; speedup vs baseline: 1.5996x; 1.1167x over previous
//
#include <hip/hip_runtime.h>

// SpatioTemporalGAT  (N=4096, F=64, H=64, K=2 heads, O=32; temporal input unused)
//
// R2 lesson: direct global B-fragment loads had lane-stride 8KB -> 64
// transactions per load instruction -> gat_attn latency-bound at 52us
// (VALUBusy 21%, MfmaUtil 3%, HBM 9%). Fix: producers write B operands in
// MFMA fragment order so consumer loads are lane-contiguous (1KB/wave/instr).
//
// convert_w — pack LSTM weights into MFMA B-frag layout: Wpk (gates i,g,o;
//             f dead since c0=0), fcb (fc), biasg = b_ih+b_hh.
// gat_prep  — Wh[k] = X @ W_gat[k]^T (fp32); store bf16 whB in B-frag order
//             [head][f][qb][lane][j]; s_src/s_dst logit terms.
// gat_attn  — fused masked softmax + PV via mfma_f32_16x16x32_bf16.
//             No max-subtraction needed (logits bounded ~±2):
//             w = adj ? exp(lrelu(sd+ss)) : 0 ; h' = elu( (Σ_q w·Wh[q]) / Σ_q w ).
//             Writes h as bf16 [n][k*64+h].
// lstm_fc2  — gates GEMM [16x192x128] per block via MFMA + fused LSTM
//             nonlinearity + fc MFMA, coalesced store through LDS.

#define NN 4096

typedef __attribute__((ext_vector_type(8))) short bf16x8;
typedef __attribute__((ext_vector_type(4))) float f32x4;

__device__ inline unsigned short bf_rne(float f) {
    unsigned u = __float_as_uint(f);
    u += 0x7fffu + ((u >> 16) & 1u);
    return (unsigned short)(u >> 16);
}

__device__ inline float sigf(float x) { return 1.f / (1.f + __expf(-x)); }

// Wpk frag layout: idx = ((t*4+k0)*64 + lane)*8 + j ; value row jj=t*16+(lane&15)
// (packed gate row: i 0-63, g 64-127, o 128-191 -> source row i/64+g,o offset),
// k-elem m = k0*32 + (lane>>4)*8 + j.
__global__ __launch_bounds__(256) void convert_w(
    const float* __restrict__ W_ih, const float* __restrict__ b_ih,
    const float* __restrict__ b_hh, const float* __restrict__ fc_W,
    unsigned short* __restrict__ Wpk, unsigned short* __restrict__ fcb,
    float* __restrict__ biasg)
{
    const int idx = blockIdx.x * 256 + threadIdx.x;
    if (idx < 24576) {
        const int j = idx & 7, lane = (idx >> 3) & 63;
        const int k0 = (idx >> 9) & 3, t = idx >> 11;       // t: 12 N-tiles
        const int jj = t * 16 + (lane & 15);                // packed gate row
        const int m = k0 * 32 + (lane >> 4) * 8 + j;
        const int sr = (jj < 64) ? jj : 64 + jj;            // skip f rows
        Wpk[idx] = bf_rne(W_ih[sr * 128 + m]);
    } else if (idx < 26624) {
        const int o = idx - 24576;                          // fc frag: 2 tiles
        const int j = o & 7, lane = (o >> 3) & 63;
        const int k0 = (o >> 9) & 1, t = o >> 10;
        const int row = t * 16 + (lane & 15);
        const int m = k0 * 32 + (lane >> 4) * 8 + j;
        fcb[o] = bf_rne(fc_W[row * 64 + m]);
    } else if (idx < 26816) {
        const int j = idx - 26624;
        const int sr = (j < 64) ? j : 64 + j;
        biasg[j] = b_ih[sr] + b_hh[sr];
    }
}

__global__ __launch_bounds__(256) void gat_prep(
    const float* __restrict__ X, const float* __restrict__ Wg,
    const float* __restrict__ a_src, const float* __restrict__ a_dst,
    unsigned short* __restrict__ whB, float* __restrict__ ssrc,
    float* __restrict__ sdst)
{
    __shared__ float X_lds[64][64];
    __shared__ float Wh_lds[64][65];   // +1 pad: conflict-free column reads
    __shared__ float spart[64][4][2];
    const int t = threadIdx.x;
    const int n0 = blockIdx.x * 64;
#pragma unroll
    for (int i = 0; i < 16; ++i) {
        int idx = t + i * 256;
        X_lds[idx >> 6][idx & 63] = X[n0 * 64 + idx];
    }
    __syncthreads();
    const int h = t & 63, rg = t >> 6;
    for (int k = 0; k < 2; ++k) {
        float acc[16];
#pragma unroll
        for (int r = 0; r < 16; ++r) acc[r] = 0.f;
        for (int f0 = 0; f0 < 64; f0 += 4) {
            const float4 w4 = *(const float4*)&Wg[(k * 64 + h) * 64 + f0];
#pragma unroll
            for (int r = 0; r < 16; ++r) {
                const float4 x4 = *(const float4*)&X_lds[rg * 16 + r][f0];
                acc[r] += w4.x * x4.x + w4.y * x4.y + w4.z * x4.z + w4.w * x4.w;
            }
        }
        if (k) __syncthreads();   // protect previous head's spart readers
#pragma unroll
        for (int r = 0; r < 16; ++r) Wh_lds[rg * 16 + r][h] = acc[r];
        __syncthreads();
        {   // per-node logit terms (partial over 16 h each)
            const int r = t & 63, qa = t >> 6;
            float ps = 0.f, pd = 0.f;
#pragma unroll
            for (int i = 0; i < 16; ++i) {
                const int hh = qa * 16 + i;
                const float v = Wh_lds[r][hh];
                ps += v * a_src[k * 64 + hh];
                pd += v * a_dst[k * 64 + hh];
            }
            spart[r][qa][0] = ps;
            spart[r][qa][1] = pd;
        }
        {   // bf16 store in MFMA B-frag order:
            // element (k,h,q): f=h>>4, n=h&15, qb=q>>5, qg=(q>>3)&3, j=q&7
            // flat = ((k*4+f)*128+qb)*512 + (qg*16+n)*8 + j
#pragma unroll
            for (int pid = t; pid < 512; pid += 256) {
                const int n = pid & 15, qg = (pid >> 4) & 3;
                const int qb_loc = (pid >> 6) & 1, f = pid >> 7;
                const int qb = (n0 >> 5) + qb_loc;
                unsigned pk[4];
#pragma unroll
                for (int i = 0; i < 4; ++i) {
                    const int r = qb_loc * 32 + qg * 8 + 2 * i;
                    unsigned lo = bf_rne(Wh_lds[r][f * 16 + n]);
                    unsigned hi = bf_rne(Wh_lds[r + 1][f * 16 + n]);
                    pk[i] = lo | (hi << 16);
                }
                uint4* dst = (uint4*)&whB[(((k * 4 + f) * 128 + qb) * 512) + (qg * 16 + n) * 8];
                *dst = make_uint4(pk[0], pk[1], pk[2], pk[3]);
            }
        }
        __syncthreads();
        if (t < 64) {
            float s0 = spart[t][0][0] + spart[t][1][0] + spart[t][2][0] + spart[t][3][0];
            float s1 = spart[t][0][1] + spart[t][1][1] + spart[t][2][1] + spart[t][3][1];
            ssrc[k * NN + n0 + t] = s0;
            sdst[k * NN + n0 + t] = s1;
        }
    }
}

__global__ __launch_bounds__(1024) void gat_attn(
    const int* __restrict__ adj, const unsigned short* __restrict__ whB,
    const float* __restrict__ ssrc, const float* __restrict__ sdst,
    unsigned short* __restrict__ h_bf)
{
    __shared__ float S_all[16][2][16][64];   // 128 KB: per-wave partial PV
    __shared__ float z_all[16][2][16];       // per-wave partial denominators
    const int tid = threadIdx.x;
    const int wave = tid >> 6, lane = tid & 63;
    const int rloc = lane & 15, qg = lane >> 4;
    const int p = blockIdx.x * 16 + rloc;          // A-frag row for this lane
    const int* __restrict__ adj_row = adj + (long)p * NN;
    const float sd0 = sdst[p], sd1 = sdst[NN + p];
    const unsigned short* __restrict__ whB_l = whB + lane * 8;

    f32x4 acc[2][4];
#pragma unroll
    for (int k = 0; k < 2; ++k)
#pragma unroll
        for (int f = 0; f < 4; ++f)
            acc[k][f] = (f32x4){0.f, 0.f, 0.f, 0.f};
    float z0 = 0.f, z1 = 0.f;

    const int qbase = wave * 256;   // each wave owns a 256-wide q slice
    for (int chunk = 0; chunk < 4; ++chunk) {
#pragma unroll
        for (int kk = 0; kk < 2; ++kk) {       // two K=32 steps per 64-q chunk
            const int q0 = qbase + chunk * 64 + kk * 32 + qg * 8;
            const int qb = wave * 8 + chunk * 2 + kk;
            const int4 a0 = *(const int4*)(adj_row + q0);
            const int4 a1 = *(const int4*)(adj_row + q0 + 4);
            const float4 sa0 = *(const float4*)(ssrc + q0);
            const float4 sa1 = *(const float4*)(ssrc + q0 + 4);
            const float4 sb0 = *(const float4*)(ssrc + NN + q0);
            const float4 sb1 = *(const float4*)(ssrc + NN + q0 + 4);
            const int am[8] = {a0.x, a0.y, a0.z, a0.w, a1.x, a1.y, a1.z, a1.w};
            const float s0v[8] = {sa0.x, sa0.y, sa0.z, sa0.w, sa1.x, sa1.y, sa1.z, sa1.w};
            const float s1v[8] = {sb0.x, sb0.y, sb0.z, sb0.w, sb1.x, sb1.y, sb1.z, sb1.w};
            union { bf16x8 v; unsigned short u[8]; } fa0, fa1;
#pragma unroll
            for (int j = 0; j < 8; ++j) {
                float e0 = sd0 + s0v[j];
                e0 = fmaxf(e0, 0.2f * e0);                      // leaky_relu(.,0.2)
                const float w0 = (am[j] > 0) ? __expf(e0) : 0.f;
                z0 += w0;
                fa0.u[j] = bf_rne(w0);
                float e1 = sd1 + s1v[j];
                e1 = fmaxf(e1, 0.2f * e1);
                const float w1 = (am[j] > 0) ? __expf(e1) : 0.f;
                z1 += w1;
                fa1.u[j] = bf_rne(w1);
            }
#pragma unroll
            for (int f = 0; f < 4; ++f) {
                const bf16x8 b0 = *(const bf16x8*)(whB_l + ((f * 128 + qb) << 9));
                acc[0][f] = __builtin_amdgcn_mfma_f32_16x16x32_bf16(fa0.v, b0, acc[0][f], 0, 0, 0);
                const bf16x8 b1 = *(const bf16x8*)(whB_l + (((4 + f) * 128 + qb) << 9));
                acc[1][f] = __builtin_amdgcn_mfma_f32_16x16x32_bf16(fa1.v, b1, acc[1][f], 0, 0, 0);
            }
        }
    }
    // z: sum the 4 q-groups (lanes l, l^16, l^32, l^48 share a row)
    z0 += __shfl_xor(z0, 16); z0 += __shfl_xor(z0, 32);
    z1 += __shfl_xor(z1, 16); z1 += __shfl_xor(z1, 32);
    if (lane < 16) { z_all[wave][0][lane] = z0; z_all[wave][1][lane] = z1; }
    // D-frag layout: row=(l>>4)*4+j, col=l&15
#pragma unroll
    for (int k = 0; k < 2; ++k)
#pragma unroll
        for (int f = 0; f < 4; ++f)
#pragma unroll
            for (int j = 0; j < 4; ++j)
                S_all[wave][k][qg * 4 + j][f * 16 + rloc] = acc[k][f][j];
    __syncthreads();
    // combine 16 wave-partials, normalize, elu, write h_bf[n][k*64+h] (bf16)
#pragma unroll
    for (int i = 0; i < 2; ++i) {
        const int idx = tid + i * 1024;
        const int k = idx >> 10, rr = (idx >> 6) & 15, hh = idx & 63;
        float s = 0.f, z = 0.f;
#pragma unroll
        for (int w = 0; w < 16; ++w) {
            s += S_all[w][k][rr][hh];
            z += z_all[w][k][rr];
        }
        float v = s / z;
        v = v > 0.f ? v : expm1f(v);
        h_bf[(blockIdx.x * 16 + rr) * 128 + k * 64 + hh] = bf_rne(v);
    }
}

// One wave per block, 16 nodes. gates[16,192] = h[16,128] @ Wpk^T via 48 MFMA;
// i/g/o of the same (node,h) live in the same lane (tiles t, 4+t, 8+t), so the
// LSTM nonlinearity is pure per-lane VALU. Then fc via 4 MFMA.
__global__ __launch_bounds__(64) void lstm_fc2(
    const unsigned short* __restrict__ h_bf, const unsigned short* __restrict__ Wpk,
    const unsigned short* __restrict__ fcb, const float* __restrict__ biasg,
    const float* __restrict__ fc_b, float* __restrict__ out)
{
    __shared__ unsigned short ht_lds[16][72];   // pad 72: bank-spread
    __shared__ float out_lds[16][32];
    const int l = threadIdx.x;
    const int c = l & 15, g4 = l >> 4;
    const int n0 = blockIdx.x * 16;

    f32x4 acc[12];
#pragma unroll
    for (int t = 0; t < 12; ++t) acc[t] = (f32x4){0.f, 0.f, 0.f, 0.f};
#pragma unroll
    for (int k0 = 0; k0 < 4; ++k0) {
        const bf16x8 afrag = *(const bf16x8*)&h_bf[(n0 + c) * 128 + k0 * 32 + g4 * 8];
#pragma unroll
        for (int t = 0; t < 12; ++t) {
            const bf16x8 b = *(const bf16x8*)&Wpk[((t * 4 + k0) * 64 + l) * 8];
            acc[t] = __builtin_amdgcn_mfma_f32_16x16x32_bf16(afrag, b, acc[t], 0, 0, 0);
        }
    }
    // D-frag: row(node) = g4*4+j, col = c. gate value for (node, h=t*16+c).
#pragma unroll
    for (int t = 0; t < 4; ++t) {
        const float bi = biasg[t * 16 + c];
        const float bg = biasg[64 + t * 16 + c];
        const float bo = biasg[128 + t * 16 + c];
#pragma unroll
        for (int j = 0; j < 4; ++j) {
            const float iv = acc[t][j] + bi;
            const float gv = acc[4 + t][j] + bg;
            const float ov = acc[8 + t][j] + bo;
            const float cc = sigf(iv) * tanhf(gv);
            const float ht = sigf(ov) * tanhf(cc);
            ht_lds[g4 * 4 + j][t * 16 + c] = bf_rne(ht);
        }
    }
    __syncthreads();
    f32x4 acc2[2];
#pragma unroll
    for (int t = 0; t < 2; ++t) acc2[t] = (f32x4){0.f, 0.f, 0.f, 0.f};
#pragma unroll
    for (int k0 = 0; k0 < 2; ++k0) {
        const bf16x8 a2 = *(const bf16x8*)&ht_lds[c][k0 * 32 + g4 * 8];
#pragma unroll
        for (int t = 0; t < 2; ++t) {
            const bf16x8 b2 = *(const bf16x8*)&fcb[((t * 2 + k0) * 64 + l) * 8];
            acc2[t] = __builtin_amdgcn_mfma_f32_16x16x32_bf16(a2, b2, acc2[t], 0, 0, 0);
        }
    }
#pragma unroll
    for (int t = 0; t < 2; ++t) {
        const float fb = fc_b[t * 16 + c];
#pragma unroll
        for (int j = 0; j < 4; ++j)
            out_lds[g4 * 4 + j][t * 16 + c] = acc2[t][j] + fb;
    }
    __syncthreads();
#pragma unroll
    for (int i = 0; i < 8; ++i) {
        const int idx = l + i * 64;
        out[n0 * 32 + idx] = out_lds[idx >> 5][idx & 31];
    }
}

extern "C" void kernel_launch(void* const* d_in, const int* in_sizes, int n_in,
                              void* d_out, int out_size, void* d_ws, size_t ws_size,
                              hipStream_t stream) {
    const float* X     = (const float*)d_in[0];
    const int*   adj   = (const int*)d_in[1];
    // d_in[2] temporal_features: unused by the reference
    const float* Wg    = (const float*)d_in[3];
    const float* a_src = (const float*)d_in[4];
    const float* a_dst = (const float*)d_in[5];
    const float* W_ih  = (const float*)d_in[6];
    // d_in[7] W_hh: unused (h0 == 0)
    const float* b_ih  = (const float*)d_in[8];
    const float* b_hh  = (const float*)d_in[9];
    const float* fc_W  = (const float*)d_in[10];
    const float* fc_b  = (const float*)d_in[11];
    float* out = (float*)d_out;

    char* ws = (char*)d_ws;
    unsigned short* whB = (unsigned short*)ws;                     // 1 MB
    float* ssrc = (float*)(ws + (1 << 20));                        // 32 KB
    float* sdst = (float*)(ws + (1 << 20) + (32 << 10));           // 32 KB
    unsigned short* h_bf = (unsigned short*)(ws + (1 << 20) + (64 << 10)); // 1 MB
    char* ws2 = ws + (2 << 20) + (64 << 10);
    unsigned short* Wpk = (unsigned short*)ws2;                    // 48 KB
    unsigned short* fcb = (unsigned short*)(ws2 + (48 << 10));     // 4 KB
    float* biasg = (float*)(ws2 + (52 << 10));                     // 768 B

    hipLaunchKernelGGL(convert_w, dim3(105), dim3(256), 0, stream,
                       W_ih, b_ih, b_hh, fc_W, Wpk, fcb, biasg);
    hipLaunchKernelGGL(gat_prep, dim3(64), dim3(256), 0, stream,
                       X, Wg, a_src, a_dst, whB, ssrc, sdst);
    hipLaunchKernelGGL(gat_attn, dim3(256), dim3(1024), 0, stream,
                       adj, whB, ssrc, sdst, h_bf);
    hipLaunchKernelGGL(lstm_fc2, dim3(256), dim3(64), 0, stream,
                       h_bf, Wpk, fcb, biasg, fc_b, out);
}

// Round 4
// 62.514 us; speedup vs baseline: 1.7711x; 1.1072x over previous
//
#include <hip/hip_runtime.h>

// SpatioTemporalGAT  (N=4096, F=64, H=64, K=2 heads, O=32; temporal input unused)
//
// R3 lesson: gat_attn was limited by adj cold-miss fan-out (16-row scattered
// int4 reads -> ~4K HBM misses/CU serialized by MSHR depth) + thin-occupancy
// lstm_fc2 (1 wave/CU). Fix: (1) per-block coalesced adj->bit conversion via
// __ballot into LDS (adj leaves HBM exactly once, streaming); (2) fuse the
// LSTM+fc into gat_attn's epilogue (block already holds its 16-node h tile).
//
// convert_w — pack LSTM weights into MFMA B-frag layout: Wpk (gates i,g,o;
//             f dead since c0=0), fcb (fc), biasg = b_ih+b_hh.
// gat_prep  — Wh[k] = X @ W_gat[k]^T (fp32); store bf16 whB in B-frag order;
//             s_src/s_dst logit terms.
// gat_attn  — phase 0: adj rows -> LDS bitmask (coalesced u32 + ballot).
//             main: fused masked softmax + PV via mfma_f32_16x16x32_bf16,
//             w = bit ? exp(lrelu(sd+ss)) : 0 (no max-sub: logits bounded ~2).
//             epilogue: combine wave partials, elu -> h tile in LDS (bf16),
//             gates GEMM (12 waves) + LSTM nonlin + fc GEMM (2 waves) -> out.

#define NN 4096

typedef __attribute__((ext_vector_type(8))) short bf16x8;
typedef __attribute__((ext_vector_type(4))) float f32x4;

__device__ inline unsigned short bf_rne(float f) {
    unsigned u = __float_as_uint(f);
    u += 0x7fffu + ((u >> 16) & 1u);
    return (unsigned short)(u >> 16);
}

__device__ inline float sigf(float x) { return 1.f / (1.f + __expf(-x)); }

// Wpk frag layout: idx = ((t*4+k0)*64 + lane)*8 + j ; packed gate row
// jj = t*16+(lane&15) (i 0-63, g 64-127, o 128-191), k m = k0*32+(lane>>4)*8+j.
__global__ __launch_bounds__(256) void convert_w(
    const float* __restrict__ W_ih, const float* __restrict__ b_ih,
    const float* __restrict__ b_hh, const float* __restrict__ fc_W,
    unsigned short* __restrict__ Wpk, unsigned short* __restrict__ fcb,
    float* __restrict__ biasg)
{
    const int idx = blockIdx.x * 256 + threadIdx.x;
    if (idx < 24576) {
        const int j = idx & 7, lane = (idx >> 3) & 63;
        const int k0 = (idx >> 9) & 3, t = idx >> 11;
        const int jj = t * 16 + (lane & 15);
        const int m = k0 * 32 + (lane >> 4) * 8 + j;
        const int sr = (jj < 64) ? jj : 64 + jj;            // skip f rows
        Wpk[idx] = bf_rne(W_ih[sr * 128 + m]);
    } else if (idx < 26624) {
        const int o = idx - 24576;                          // fc frag: 2 tiles
        const int j = o & 7, lane = (o >> 3) & 63;
        const int k0 = (o >> 9) & 1, t = o >> 10;
        const int row = t * 16 + (lane & 15);
        const int m = k0 * 32 + (lane >> 4) * 8 + j;
        fcb[o] = bf_rne(fc_W[row * 64 + m]);
    } else if (idx < 26816) {
        const int j = idx - 26624;
        const int sr = (j < 64) ? j : 64 + j;
        biasg[j] = b_ih[sr] + b_hh[sr];
    }
}

__global__ __launch_bounds__(256) void gat_prep(
    const float* __restrict__ X, const float* __restrict__ Wg,
    const float* __restrict__ a_src, const float* __restrict__ a_dst,
    unsigned short* __restrict__ whB, float* __restrict__ ssrc,
    float* __restrict__ sdst)
{
    __shared__ float X_lds[64][64];
    __shared__ float Wh_lds[64][65];
    __shared__ float spart[64][4][2];
    const int t = threadIdx.x;
    const int n0 = blockIdx.x * 64;
#pragma unroll
    for (int i = 0; i < 16; ++i) {
        int idx = t + i * 256;
        X_lds[idx >> 6][idx & 63] = X[n0 * 64 + idx];
    }
    __syncthreads();
    const int h = t & 63, rg = t >> 6;
    for (int k = 0; k < 2; ++k) {
        float acc[16];
#pragma unroll
        for (int r = 0; r < 16; ++r) acc[r] = 0.f;
        for (int f0 = 0; f0 < 64; f0 += 4) {
            const float4 w4 = *(const float4*)&Wg[(k * 64 + h) * 64 + f0];
#pragma unroll
            for (int r = 0; r < 16; ++r) {
                const float4 x4 = *(const float4*)&X_lds[rg * 16 + r][f0];
                acc[r] += w4.x * x4.x + w4.y * x4.y + w4.z * x4.z + w4.w * x4.w;
            }
        }
        if (k) __syncthreads();
#pragma unroll
        for (int r = 0; r < 16; ++r) Wh_lds[rg * 16 + r][h] = acc[r];
        __syncthreads();
        {   // per-node logit terms (partial over 16 h each)
            const int r = t & 63, qa = t >> 6;
            float ps = 0.f, pd = 0.f;
#pragma unroll
            for (int i = 0; i < 16; ++i) {
                const int hh = qa * 16 + i;
                const float v = Wh_lds[r][hh];
                ps += v * a_src[k * 64 + hh];
                pd += v * a_dst[k * 64 + hh];
            }
            spart[r][qa][0] = ps;
            spart[r][qa][1] = pd;
        }
        {   // bf16 store in MFMA B-frag order:
            // flat = ((k*4+f)*128+qb)*512 + (qg*16+n)*8 + j
#pragma unroll
            for (int pid = t; pid < 512; pid += 256) {
                const int n = pid & 15, qg = (pid >> 4) & 3;
                const int qb_loc = (pid >> 6) & 1, f = pid >> 7;
                const int qb = (n0 >> 5) + qb_loc;
                unsigned pk[4];
#pragma unroll
                for (int i = 0; i < 4; ++i) {
                    const int r = qb_loc * 32 + qg * 8 + 2 * i;
                    unsigned lo = bf_rne(Wh_lds[r][f * 16 + n]);
                    unsigned hi = bf_rne(Wh_lds[r + 1][f * 16 + n]);
                    pk[i] = lo | (hi << 16);
                }
                uint4* dst = (uint4*)&whB[(((k * 4 + f) * 128 + qb) * 512) + (qg * 16 + n) * 8];
                *dst = make_uint4(pk[0], pk[1], pk[2], pk[3]);
            }
        }
        __syncthreads();
        if (t < 64) {
            float s0 = spart[t][0][0] + spart[t][1][0] + spart[t][2][0] + spart[t][3][0];
            float s1 = spart[t][0][1] + spart[t][1][1] + spart[t][2][1] + spart[t][3][1];
            ssrc[k * NN + n0 + t] = s0;
            sdst[k * NN + n0 + t] = s1;
        }
    }
}

__global__ __launch_bounds__(1024) void gat_attn(
    const int* __restrict__ adj, const unsigned short* __restrict__ whB,
    const float* __restrict__ ssrc, const float* __restrict__ sdst,
    const unsigned short* __restrict__ Wpk, const unsigned short* __restrict__ fcb,
    const float* __restrict__ biasg, const float* __restrict__ fc_b,
    float* __restrict__ out)
{
    __shared__ float S_all[16][2][16][64];              // 128 KB wave partials
    __shared__ float z_all[16][2][16];                  // 2 KB
    __shared__ unsigned long long bits_lds[16][65];     // 8.3 KB adj bitmask
    // post-combine aliases into dead S_all space:
    unsigned short* h_lds = (unsigned short*)&S_all[0][0][0][0];        // [16][136] bf16
    float* gate_lds = (float*)((char*)&S_all[0][0][0][0] + 4608);       // [3][16][68] f32

    const int tid = threadIdx.x;
    const int wave = tid >> 6, lane = tid & 63;
    const int rloc = lane & 15, qg = lane >> 4;
    const int p0 = blockIdx.x * 16;
    const int p = p0 + rloc;

    // ---- phase 0: adj rows -> bit table (coalesced stream + ballot) ----
    {
        const int* __restrict__ arow = adj + (long)(p0 + wave) * NN;
        unsigned long long myw = 0ull;
#pragma unroll 8
        for (int it = 0; it < 64; ++it) {
            const int v = arow[it * 64 + lane];
            const unsigned long long bal = __ballot(v != 0);
            if (lane == it) myw = bal;
        }
        bits_lds[wave][lane] = myw;   // row (p0+wave), bits [lane*64, lane*64+64)
    }
    __syncthreads();

    const float sd0 = sdst[p], sd1 = sdst[NN + p];
    const unsigned short* __restrict__ whB_l = whB + lane * 8;

    f32x4 acc[2][4];
#pragma unroll
    for (int k = 0; k < 2; ++k)
#pragma unroll
        for (int f = 0; f < 4; ++f)
            acc[k][f] = (f32x4){0.f, 0.f, 0.f, 0.f};
    float z0 = 0.f, z1 = 0.f;

    const int qbase = wave * 256;   // each wave owns a 256-wide q slice
    for (int chunk = 0; chunk < 4; ++chunk) {
        const unsigned long long bw = bits_lds[rloc][wave * 4 + chunk];
#pragma unroll
        for (int kk = 0; kk < 2; ++kk) {       // two K=32 steps per 64-q chunk
            const int q0 = qbase + chunk * 64 + kk * 32 + qg * 8;
            const int qb = wave * 8 + chunk * 2 + kk;
            const unsigned byte8 = ((unsigned)(bw >> (kk * 32)) >> (qg * 8)) & 0xffu;
            const float4 sa0 = *(const float4*)(ssrc + q0);
            const float4 sa1 = *(const float4*)(ssrc + q0 + 4);
            const float4 sb0 = *(const float4*)(ssrc + NN + q0);
            const float4 sb1 = *(const float4*)(ssrc + NN + q0 + 4);
            const float s0v[8] = {sa0.x, sa0.y, sa0.z, sa0.w, sa1.x, sa1.y, sa1.z, sa1.w};
            const float s1v[8] = {sb0.x, sb0.y, sb0.z, sb0.w, sb1.x, sb1.y, sb1.z, sb1.w};
            union { bf16x8 v; unsigned short u[8]; } fa0, fa1;
#pragma unroll
            for (int j = 0; j < 8; ++j) {
                const bool on = (byte8 & (1u << j)) != 0u;
                float e0 = sd0 + s0v[j];
                e0 = fmaxf(e0, 0.2f * e0);                      // leaky_relu(.,0.2)
                const float w0 = on ? __expf(e0) : 0.f;
                z0 += w0;
                fa0.u[j] = bf_rne(w0);
                float e1 = sd1 + s1v[j];
                e1 = fmaxf(e1, 0.2f * e1);
                const float w1 = on ? __expf(e1) : 0.f;
                z1 += w1;
                fa1.u[j] = bf_rne(w1);
            }
#pragma unroll
            for (int f = 0; f < 4; ++f) {
                const bf16x8 b0 = *(const bf16x8*)(whB_l + ((f * 128 + qb) << 9));
                acc[0][f] = __builtin_amdgcn_mfma_f32_16x16x32_bf16(fa0.v, b0, acc[0][f], 0, 0, 0);
                const bf16x8 b1 = *(const bf16x8*)(whB_l + (((4 + f) * 128 + qb) << 9));
                acc[1][f] = __builtin_amdgcn_mfma_f32_16x16x32_bf16(fa1.v, b1, acc[1][f], 0, 0, 0);
            }
        }
    }
    // z: sum the 4 q-groups (lanes l, l^16, l^32, l^48 share a row)
    z0 += __shfl_xor(z0, 16); z0 += __shfl_xor(z0, 32);
    z1 += __shfl_xor(z1, 16); z1 += __shfl_xor(z1, 32);
    if (lane < 16) { z_all[wave][0][lane] = z0; z_all[wave][1][lane] = z1; }
    // D-frag layout: row=(l>>4)*4+j, col=l&15
#pragma unroll
    for (int k = 0; k < 2; ++k)
#pragma unroll
        for (int f = 0; f < 4; ++f)
#pragma unroll
            for (int j = 0; j < 4; ++j)
                S_all[wave][k][qg * 4 + j][f * 16 + rloc] = acc[k][f][j];
    __syncthreads();
    // combine 16 wave-partials, normalize, elu -> registers
    float vreg[2]; int vk[2], vr[2], vh[2];
#pragma unroll
    for (int i = 0; i < 2; ++i) {
        const int idx = tid + i * 1024;
        const int k = idx >> 10, rr = (idx >> 6) & 15, hh = idx & 63;
        float s = 0.f, z = 0.f;
#pragma unroll
        for (int w = 0; w < 16; ++w) {
            s += S_all[w][k][rr][hh];
            z += z_all[w][k][rr];
        }
        float v = s / z;
        vreg[i] = v > 0.f ? v : expm1f(v);
        vk[i] = k; vr[i] = rr; vh[i] = hh;
    }
    __syncthreads();    // all S_all reads done; safe to reuse as h_lds/gate_lds
    // h tile bf16 [node][k*64+h], padded row 136 (272B, 16B-aligned rows)
#pragma unroll
    for (int i = 0; i < 2; ++i)
        h_lds[vr[i] * 136 + vk[i] * 64 + vh[i]] = bf_rne(vreg[i]);
    __syncthreads();

    // ---- fused LSTM gates GEMM: 12 waves, one 16-col gate tile each ----
    const int c = lane & 15, g4 = lane >> 4;
    if (wave < 12) {
        const int t = wave;
        f32x4 ga = (f32x4){0.f, 0.f, 0.f, 0.f};
#pragma unroll
        for (int k0 = 0; k0 < 4; ++k0) {
            const bf16x8 a = *(const bf16x8*)&h_lds[c * 136 + k0 * 32 + g4 * 8];
            const bf16x8 b = *(const bf16x8*)&Wpk[((t * 4 + k0) * 64 + lane) * 8];
            ga = __builtin_amdgcn_mfma_f32_16x16x32_bf16(a, b, ga, 0, 0, 0);
        }
        const float bb = biasg[t * 16 + c];
#pragma unroll
        for (int j = 0; j < 4; ++j)
            gate_lds[(t >> 2) * 1088 + (g4 * 4 + j) * 68 + (t & 3) * 16 + c] = ga[j] + bb;
    }
    __syncthreads();
    // ---- LSTM nonlinearity: ht = sig(o)*tanh(sig(i)*tanh(g)) ----
    if (tid < 1024) {
        const int n = tid >> 6, hh = tid & 63;
        const float iv = gate_lds[n * 68 + hh];
        const float gv = gate_lds[1088 + n * 68 + hh];
        const float ov = gate_lds[2176 + n * 68 + hh];
        const float cv = sigf(iv) * tanhf(gv);
        const float htv = sigf(ov) * tanhf(cv);
        h_lds[n * 136 + hh] = bf_rne(htv);   // reuse h_lds (gates consumed h)
    }
    __syncthreads();
    // ---- fc GEMM: waves 0,1 -> out[16 nodes][32] ----
    if (wave < 2) {
        const int t2 = wave;
        f32x4 fa = (f32x4){0.f, 0.f, 0.f, 0.f};
#pragma unroll
        for (int k0 = 0; k0 < 2; ++k0) {
            const bf16x8 a = *(const bf16x8*)&h_lds[c * 136 + k0 * 32 + g4 * 8];
            const bf16x8 b = *(const bf16x8*)&fcb[((t2 * 2 + k0) * 64 + lane) * 8];
            fa = __builtin_amdgcn_mfma_f32_16x16x32_bf16(a, b, fa, 0, 0, 0);
        }
        const float fb = fc_b[t2 * 16 + c];
#pragma unroll
        for (int j = 0; j < 4; ++j)
            out[(p0 + g4 * 4 + j) * 32 + t2 * 16 + c] = fa[j] + fb;
    }
}

extern "C" void kernel_launch(void* const* d_in, const int* in_sizes, int n_in,
                              void* d_out, int out_size, void* d_ws, size_t ws_size,
                              hipStream_t stream) {
    const float* X     = (const float*)d_in[0];
    const int*   adj   = (const int*)d_in[1];
    // d_in[2] temporal_features: unused by the reference
    const float* Wg    = (const float*)d_in[3];
    const float* a_src = (const float*)d_in[4];
    const float* a_dst = (const float*)d_in[5];
    const float* W_ih  = (const float*)d_in[6];
    // d_in[7] W_hh: unused (h0 == 0)
    const float* b_ih  = (const float*)d_in[8];
    const float* b_hh  = (const float*)d_in[9];
    const float* fc_W  = (const float*)d_in[10];
    const float* fc_b  = (const float*)d_in[11];
    float* out = (float*)d_out;

    char* ws = (char*)d_ws;
    unsigned short* whB = (unsigned short*)ws;                     // 1 MB
    float* ssrc = (float*)(ws + (1 << 20));                        // 32 KB
    float* sdst = (float*)(ws + (1 << 20) + (32 << 10));           // 32 KB
    char* ws2 = ws + (1 << 20) + (64 << 10);
    unsigned short* Wpk = (unsigned short*)ws2;                    // 48 KB
    unsigned short* fcb = (unsigned short*)(ws2 + (48 << 10));     // 4 KB
    float* biasg = (float*)(ws2 + (52 << 10));                     // 768 B

    hipLaunchKernelGGL(convert_w, dim3(105), dim3(256), 0, stream,
                       W_ih, b_ih, b_hh, fc_W, Wpk, fcb, biasg);
    hipLaunchKernelGGL(gat_prep, dim3(64), dim3(256), 0, stream,
                       X, Wg, a_src, a_dst, whB, ssrc, sdst);
    hipLaunchKernelGGL(gat_attn, dim3(256), dim3(1024), 0, stream,
                       adj, whB, ssrc, sdst, Wpk, fcb, biasg, fc_b, out);
}